// Round 10
// baseline (95.753 us; speedup 1.0000x reference)
//
#include <hip/hip_runtime.h>
#include <math.h>

#define AN 4096
#define CN 8
#define FN 64
#define ACN (AN*CN)   // 32768
#define NSEG 4        // column segments; k2 grid = 8*32*4 = 1024 (one resident batch)
#define ITERS 16      // 64-col tiles per block: 4096/NSEG/64

typedef __attribute__((ext_vector_type(8))) short bf16x8;
typedef __attribute__((ext_vector_type(4))) float f32x4;

// Direct global->LDS DMA, 16B per lane: lane l writes lds_dest + l*16.
#define GLL16(gsrc, ldst) \
    __builtin_amdgcn_global_load_lds( \
        (const __attribute__((address_space(1))) void*)(gsrc), \
        (__attribute__((address_space(3))) void*)(ldst), 16, 0, 0)

__device__ inline unsigned short f2bf(float f) {
    unsigned u = __float_as_uint(f);
    unsigned r = ((u >> 16) & 1) + 0x7FFFu;   // round-to-nearest-even
    return (unsigned short)((u + r) >> 16);
}

// ---------------------------------------------------------------------------
// K1: normalize -> xnb bf16 [c][a][f] + inv[a*8+c] fp32 inverse norms.
// k3 recomputes x*inv (identical multiply, bit-exact).
// ---------------------------------------------------------------------------
__global__ __launch_bounds__(256) void k1_normalize(const float* __restrict__ x,
                                                    unsigned short* __restrict__ xnb,
                                                    float* __restrict__ inv)
{
    int tid  = threadIdx.x;
    int grp  = tid >> 4;
    int slot = tid & 15;
    #pragma unroll
    for (int s = 0; s < 4; ++s) {
        int V = blockIdx.x * 64 + s * 16 + grp;      // 0..32767 = a*8+c
        const float4 v = *(const float4*)(x + (size_t)V * FN + slot * 4);
        float ss = v.x*v.x + v.y*v.y + v.z*v.z + v.w*v.w;
        ss += __shfl_xor(ss, 1);
        ss += __shfl_xor(ss, 2);
        ss += __shfl_xor(ss, 4);
        ss += __shfl_xor(ss, 8);
        float sc = 1.0f / fmaxf(sqrtf(ss), 1e-6f);
        int a = V >> 3, c = V & 7;
        ushort4 ob;
        ob.x = f2bf(v.x * sc); ob.y = f2bf(v.y * sc);
        ob.z = f2bf(v.z * sc); ob.w = f2bf(v.w * sc);
        *(ushort4*)(xnb + ((size_t)c * AN + a) * FN + slot * 4) = ob;
        if (slot == 0) inv[V] = sc;
    }
}

// ---------------------------------------------------------------------------
// K2: OCCUPANCY REDESIGN (r9 post-mortem: real-regime limiter is latency
// exposure at 2-3 waves/SIMD; deep-queue replication proved the bodies get
// faster only when the CU has many blocks in flight. Fix: make 4 blocks/CU
// CO-RESIDENT in one batch).
//   - 2x2 wave layout (wr,wc), 128 rows x 64-col tiles -> VGPR ~100
//     (afr[4][2] + acc[4][2] + bestp[16]) under the 128 cap of (256,4).
//   - LDS 32KB: A 16KB | B0 8KB | B1 8KB -> 4 blocks/CU (LDS-wise 5, VGPR 4).
//   - grid 1024 = 8c x 32rt x 4seg: every block resident from t=0.
//   - staging: verified gload_lds pre-swizzled scheme; per-iter
//     __syncthreads (drain overlaps the 3 other resident blocks).
//   - full unroll: buffer offsets compile-time; MFMA/argmax/diag logic
//     byte-identical to the verified r6/r9 bodies.
// ---------------------------------------------------------------------------
__global__ __launch_bounds__(256, 4) void k2_argmax(const unsigned short* __restrict__ xnb,
                                                    unsigned int* __restrict__ pP)
{
    __shared__ char ldsc[32768];   // A [0,16K) | B0 [16K,24K) | B1 [24K,32K)

    int blk  = blockIdx.x;             // 0..1023
    int seg  = blk & (NSEG - 1);
    int rt   = (blk >> 2) & 31;
    int c    = blk >> 7;               // 0..7
    int a0   = rt * 128;
    int col0 = seg * 1024;

    const char* __restrict__ Xc = (const char*)(xnb + (size_t)c * AN * FN); // row r at byte r*128

    int tid  = threadIdx.x;
    int lane = tid & 63;
    int w    = tid >> 6;      // wave 0..3
    int wr   = w >> 1;        // row half 0..1
    int wc   = w & 1;         // col half 0..1
    int l15  = lane & 15;
    int quad = lane >> 4;
    int srow = lane >> 3;     // 0..7
    int sslot = lane & 7;

    // per-lane global staging offset within an 8-row group (chunk pre-swizzled:
    // row&7 == srow for all staged rows)
    int gl_lane = srow * 128 + ((sslot ^ srow) << 4);

    // ---- stage A tile: wave w stages rows w*32..w*32+32 (4 issues) ----
    const char* gA = Xc + (size_t)(a0 + w * 32) * 128 + gl_lane;
    char* ldsA = ldsc + w * 4096;
    GLL16(gA,        ldsA);
    GLL16(gA + 1024, ldsA + 1024);
    GLL16(gA + 2048, ldsA + 2048);
    GLL16(gA + 3072, ldsA + 3072);

    // ---- B staging: tile t (64 rows x 128B = 8KB), wave w issues s=0,1
    //      covering tile-rows {w*8..+8} and {32+w*8..+8} ----
    const char* gB = Xc + (size_t)col0 * 128 + (size_t)w * 1024 + gl_lane;
#define STAGE_B(T) do { \
        const char* _g = gB + (size_t)(T) * 8192; \
        char* _l = ldsc + 16384 + ((T) & 1) * 8192 + w * 1024; \
        GLL16(_g,        _l); \
        GLL16(_g + 4096, _l + 4096); \
    } while (0)

    STAGE_B(0);
    __syncthreads();          // drains all DMA; A and B0 visible to all waves

    // ---- A fragments (loop-invariant): row = wr*64 + mi*16 + l15 ----
    int ab0 = (wr * 64 + l15) * 128 + ((quad ^ (l15 & 7)) << 4);
    int ab1 = ab0 ^ 64;
    bf16x8 afr[4][2];
    #pragma unroll
    for (int mi = 0; mi < 4; ++mi) {
        afr[mi][0] = *(const bf16x8*)(ldsc + ab0 + mi * 2048);
        afr[mi][1] = *(const bf16x8*)(ldsc + ab1 + mi * 2048);
    }

    // ---- B frag bases: tile-row r = wc*32 + ni*16 + l15 ----
    int rb0 = 16384 + (wc * 32 + l15) * 128 + ((quad ^ (l15 & 7)) << 4);
    int rb1 = rb0 ^ 64;

    float bestp[16];
    #pragma unroll
    for (int i = 0; i < 16; ++i) bestp[i] = 0.0f;

    const f32x4 two = {2.0f, 2.0f, 2.0f, 2.0f};

    #pragma unroll
    for (int it = 0; it < ITERS; ++it) {
        if (it < ITERS - 1) STAGE_B(it + 1);    // into the other buffer

        const int bo = (it & 1) * 8192;         // compile-time (full unroll)

        f32x4 acc[4][2];
        #pragma unroll
        for (int ks = 0; ks < 2; ++ks) {
            #pragma unroll
            for (int ni = 0; ni < 2; ++ni) {
                bf16x8 bfr = *(const bf16x8*)(ldsc + (ks ? rb1 : rb0) + bo + ni * 2048);
                #pragma unroll
                for (int mi = 0; mi < 4; ++mi)
                    acc[mi][ni] = __builtin_amdgcn_mfma_f32_16x16x32_bf16(
                        afr[mi][ks], bfr, (ks == 0) ? two : acc[mi][ni], 0, 0, 0);
            }
        }

        // ---- packed argmax update ----
        int colblk = col0 + it * 64 + wc * 32;
        #pragma unroll
        for (int mi = 0; mi < 4; ++mi) {
            int rfrag = a0 + wr * 64 + mi * 16;
            #pragma unroll
            for (int r = 0; r < 4; ++r) {
                unsigned p0 = (__float_as_uint(acc[mi][0][r]) & 0xFFFFF000u)
                            | (unsigned)(colblk + l15);
                unsigned p1 = (__float_as_uint(acc[mi][1][r]) & 0xFFFFF000u)
                            | (unsigned)(colblk + 16 + l15);
                float c0 = __uint_as_float(p0);
                float c1 = __uint_as_float(p1);
                if (rfrag == colblk)      { if (l15 == quad * 4 + r) c0 = 0.0f; }
                if (rfrag == colblk + 16) { if (l15 == quad * 4 + r) c1 = 0.0f; }
                int bi = mi * 4 + r;
                bestp[bi] = fmaxf(fmaxf(c0, c1), bestp[bi]);
            }
        }

        __syncthreads();   // drains next-tile DMA (visibility) + guards buf reuse
    }
#undef STAGE_B

    // ---- reduce across the 16 column-lanes ----
    #pragma unroll
    for (int i = 0; i < 16; ++i) {
        float v = bestp[i];
        v = fmaxf(v, __shfl_xor(v, 1));
        v = fmaxf(v, __shfl_xor(v, 2));
        v = fmaxf(v, __shfl_xor(v, 4));
        v = fmaxf(v, __shfl_xor(v, 8));
        bestp[i] = v;
    }
    __syncthreads();                    // A region reusable
    float* red = (float*)ldsc;          // red[w][64]
    if (l15 == 0) {
        #pragma unroll
        for (int mi = 0; mi < 4; ++mi)
            #pragma unroll
            for (int r = 0; r < 4; ++r)
                red[w * 64 + mi * 16 + quad * 4 + r] = bestp[mi * 4 + r];
    }
    __syncthreads();
    if (tid < 128) {
        int wr2 = tid >> 6, r64 = tid & 63;
        float p = fmaxf(red[(2 * wr2) * 64 + r64], red[(2 * wr2 + 1) * 64 + r64]);
        int a = a0 + tid;
        pP[(size_t)seg * ACN + (size_t)a * CN + c] = __float_as_uint(p);
    }
}

// ---------------------------------------------------------------------------
// K3: merge NSEG segments, unpack index, exact fp32 distance + log, reduce.
// ---------------------------------------------------------------------------
__global__ __launch_bounds__(256) void k3_dist(const float* __restrict__ x,
                                               const float* __restrict__ inv,
                                               const unsigned int* __restrict__ pP,
                                               float* __restrict__ partials)
{
    int tid = threadIdx.x;
    int id = blockIdx.x * 256 + tid;            // a*8 + c
    float p0 = __uint_as_float(pP[id]);
    float p1 = __uint_as_float(pP[ACN + id]);
    float p2 = __uint_as_float(pP[2 * ACN + id]);
    float p3 = __uint_as_float(pP[3 * ACN + id]);
    unsigned pm = __float_as_uint(fmaxf(fmaxf(p0, p1), fmaxf(p2, p3)));
    int m = (int)(pm & 0xFFFu);
    int c = id & 7;
    int idb = m * CN + c;
    float sa = inv[id];
    float sb = inv[idb];
    const float* xa = x + (size_t)id  * FN;
    const float* xb = x + (size_t)idb * FN;
    float ss = 0.0f;
    #pragma unroll
    for (int q = 0; q < 16; ++q) {
        float4 va = *(const float4*)(xa + 4 * q);
        float4 vb = *(const float4*)(xb + 4 * q);
        float d0 = va.x * sa - vb.x * sb + 1e-6f;
        float d1 = va.y * sa - vb.y * sb + 1e-6f;
        float d2 = va.z * sa - vb.z * sb + 1e-6f;
        float d3 = va.w * sa - vb.w * sb + 1e-6f;
        ss += d0*d0 + d1*d1 + d2*d2 + d3*d3;
    }
    float val = logf(sqrtf(ss) + 1e-6f);

    float t = val;
    #pragma unroll
    for (int off = 32; off > 0; off >>= 1) t += __shfl_down(t, off);
    __shared__ float ws4[4];
    if ((tid & 63) == 0) ws4[tid >> 6] = t;
    __syncthreads();
    if (tid == 0)
        partials[blockIdx.x] = ws4[0] + ws4[1] + ws4[2] + ws4[3];
}

// ---------------------------------------------------------------------------
// K4: out = -sum(partials)/32768
// ---------------------------------------------------------------------------
__global__ __launch_bounds__(64) void k4_final(const float* __restrict__ partials,
                                               float* __restrict__ out)
{
    int t = threadIdx.x;
    float v = partials[t] + partials[t + 64];
    #pragma unroll
    for (int off = 32; off > 0; off >>= 1) v += __shfl_down(v, off);
    if (t == 0) out[0] = -v / (float)ACN;
}

extern "C" void kernel_launch(void* const* d_in, const int* in_sizes, int n_in,
                              void* d_out, int out_size, void* d_ws, size_t ws_size,
                              hipStream_t stream)
{
    const float* x = (const float*)d_in[0];
    unsigned short* xnb = (unsigned short*)d_ws;               // 4 MB bf16 [c][a][f]
    float* inv = (float*)(xnb + (size_t)AN * CN * FN);         // 128 KB inverse norms
    unsigned int* pP = (unsigned int*)(inv + ACN);             // 512 KB packed argmax (4 segs)
    float* partials = (float*)(pP + NSEG * ACN);               // 512 B

    k1_normalize<<<512, 256, 0, stream>>>(x, xnb, inv);
    k2_argmax  <<<CN * 32 * NSEG, 256, 0, stream>>>(xnb, pP);  // 8*32*4 = 1024
    k3_dist    <<<128, 256, 0, stream>>>(x, inv, pP, partials);
    k4_final   <<<1, 64, 0, stream>>>(partials, (float*)d_out);
}